// Round 18
// baseline (135.460 us; speedup 1.0000x reference)
//
#include <hip/hip_runtime.h>
#include <hip/hip_bf16.h>
#include <math.h>

#define M_NODES 50000
#define K_NBR   16
#define DIM     256
#define H_HEADS 8
#define EPS     1e-5f
#define INV_SCALE 0.17677669529663687f   // 1/sqrt(32)
#define LOG2E     1.4426950408889634f
#define NEG_IS_L2E (-0.25506150946889375f) // -INV_SCALE*log2(e)

typedef __attribute__((ext_vector_type(8))) short short8;
typedef __attribute__((ext_vector_type(4))) float f32x4;
typedef __attribute__((ext_vector_type(2))) float f32x2;
typedef __attribute__((ext_vector_type(4))) unsigned short ushort4v;

__device__ __forceinline__ unsigned short f2bf(float f) {
    unsigned x = __float_as_uint(f);
    x += 0x7FFFu + ((x >> 16) & 1u);          // round-to-nearest-even
    return (unsigned short)(x >> 16);
}
__device__ __forceinline__ unsigned cvt_pk_bf16(float lo, float hi) {
    unsigned r;
    asm volatile("v_cvt_pk_bf16_f32 %0, %1, %2" : "=v"(r) : "v"(lo), "v"(hi));
    return r;
}
__device__ __forceinline__ float bflo(unsigned int u) {   // low bf16 of dword
    return __uint_as_float(u << 16);
}
__device__ __forceinline__ float bfhi(unsigned int u) {   // high bf16 of dword
    return __uint_as_float(u & 0xFFFF0000u);
}
__device__ __forceinline__ float fast_exp2(float x) {     // v_exp_f32: 2^x
    float r; asm("v_exp_f32 %0, %1" : "=v"(r) : "v"(x)); return r;
}
__device__ __forceinline__ float fast_rcp(float x) {      // v_rcp_f32 (~1ulp)
    float r; asm("v_rcp_f32 %0, %1" : "=v"(r) : "v"(x)); return r;
}

// ---------------------------------------------------------------------------
// Kernel 0 (tiny): transposed bf16 weights + fp8 bias-sentinel row only.
// The h->bf16 pass is GONE: gemm_qk stages from fp32 h directly, attn's
// residual reads fp32 h directly (r4-r8 proven).
// ---------------------------------------------------------------------------
__global__ __launch_bounds__(256) void prep_w_kernel(
    const float* __restrict__ Wq, const float* __restrict__ Wk,
    const float* __restrict__ Wo, const float* __restrict__ bk,
    unsigned short* __restrict__ WqkT, unsigned short* __restrict__ WoT,
    unsigned char* __restrict__ Kbias8)
{
    int i = blockIdx.x * 256 + threadIdx.x;
    if (i < 512 * 256) {
        int n = i >> 8, k = i & 255;
        float v = (n < 256) ? Wq[k * 256 + n] : Wk[k * 256 + (n - 256)];
        WqkT[i] = f2bf(v);
    } else if (i < 512 * 256 + 256 * 256) {
        int j = i - 512 * 256; int n = j >> 8, k = j & 255;
        WoT[j] = f2bf(Wo[k * 256 + n]);
    } else {
        int j = i - 512 * 256 - 256 * 256;   // 0..255 (grid sized exactly)
        unsigned r8v = __builtin_amdgcn_cvt_pk_fp8_f32(bk[j], bk[j], 0, false);
        Kbias8[j] = (unsigned char)(r8v & 0xFFu);
    }
}

// ---------------------------------------------------------------------------
// GEMM QK: [Q|K] = h @ WqkT^T + [bq|bk]. A staged DIRECTLY from fp32 h with
// in-register cvt_pk_bf16 (r9 retry — now safe: 32KB LDS -> ~4 blocks/CU,
// no hb side-write). Q half -> bf16, K half -> fp8 e4m3. 128x128 tile,
// 4 waves, 16x16x32 bf16 MFMA, K in 4 chunks of 64. LDS-transpose epilogue.
// ---------------------------------------------------------------------------
__global__ __launch_bounds__(256) void gemm_qk_kernel(
    const float* __restrict__ h,
    const unsigned short* __restrict__ Bt,
    const float* __restrict__ bias0, const float* __restrict__ bias1,
    unsigned short* __restrict__ o_bf0, unsigned char* __restrict__ o_fp8)
{
    __shared__ __align__(16) char smem[32768];    // sA 16KB | sB 16KB; epilogue: C-tile
    char* sA = smem;
    char* sB = smem + 16384;
    const int m0 = blockIdx.y * 128;
    const int n0 = blockIdx.x * 128;
    const int t = threadIdx.x;
    const int lane = t & 63;
    const int w = t >> 6;
    const int wr = w >> 1, wc = w & 1;

    f32x4 acc[4][4];
#pragma unroll
    for (int a = 0; a < 4; ++a)
#pragma unroll
        for (int b = 0; b < 4; ++b) acc[a][b] = (f32x4){0.f, 0.f, 0.f, 0.f};

    const char* hf = (const char*)h;       // fp32 rows: 1024B stride
    const char* Bb = (const char*)Bt;      // bf16 rows: 512B stride

    for (int kt = 0; kt < 512; kt += 128) {  // 4 chunks of 64 elems (bf16 bytes)
#pragma unroll
        for (int i = 0; i < 4; ++i) {
            int o = i * 4096 + t * 16;
            int row = o >> 7;
            int col = o & 127;                 // bf16-byte offset within chunk
            int lo = o ^ ((row & 7) << 4);
            int ga = m0 + row; ga = (ga < M_NODES) ? ga : (M_NODES - 1);
            // load 8 fp32 from h, convert to 8 bf16, stage
            const char* src = hf + (size_t)ga * 1024 + (size_t)(kt + col) * 2;
            float4 fa = *reinterpret_cast<const float4*>(src);
            float4 fb2 = *reinterpret_cast<const float4*>(src + 16);
            union { short8 v; unsigned u[4]; } pk;
            pk.u[0] = cvt_pk_bf16(fa.x, fa.y);
            pk.u[1] = cvt_pk_bf16(fa.z, fa.w);
            pk.u[2] = cvt_pk_bf16(fb2.x, fb2.y);
            pk.u[3] = cvt_pk_bf16(fb2.z, fb2.w);
            *reinterpret_cast<short8*>(sA + lo) = pk.v;
            int gb = n0 + row;
            short8 vb = *reinterpret_cast<const short8*>(Bb + (size_t)gb * 512 + kt + col);
            *reinterpret_cast<short8*>(sB + lo) = vb;
        }
        __syncthreads();
#pragma unroll
        for (int ks = 0; ks < 2; ++ks) {
            const int kb = ks * 64 + (lane >> 4) * 16;
            short8 af[4], bfr[4];
#pragma unroll
            for (int mi = 0; mi < 4; ++mi) {
                int row = wr * 64 + mi * 16 + (lane & 15);
                af[mi] = *reinterpret_cast<const short8*>(
                    sA + ((row << 7) | (kb ^ ((row & 7) << 4))));
            }
#pragma unroll
            for (int ni = 0; ni < 4; ++ni) {
                int row = wc * 64 + ni * 16 + (lane & 15);
                bfr[ni] = *reinterpret_cast<const short8*>(
                    sB + ((row << 7) | (kb ^ ((row & 7) << 4))));
            }
#pragma unroll
            for (int mi = 0; mi < 4; ++mi)
#pragma unroll
                for (int ni = 0; ni < 4; ++ni)
                    acc[mi][ni] = __builtin_amdgcn_mfma_f32_16x16x32_bf16(
                        af[mi], bfr[ni], acc[mi][ni], 0, 0, 0);
        }
        __syncthreads();
    }

    // ---- epilogue: bias + f2bf into LDS C-tile (row*256B + col*2, XOR-swz) ----
#pragma unroll
    for (int ni = 0; ni < 4; ++ni) {
        int lcol = wc * 64 + ni * 16 + (lane & 15);
        int gcol = n0 + lcol;
        float bias = (gcol < 256) ? bias0[gcol] : bias1[gcol - 256];
#pragma unroll
        for (int mi = 0; mi < 4; ++mi) {
#pragma unroll
            for (int q = 0; q < 4; ++q) {
                int lrow = wr * 64 + mi * 16 + (lane >> 4) * 4 + q;
                int o = (lrow << 8) + lcol * 2;
                int lo = o ^ ((lrow & 7) << 4);
                *reinterpret_cast<unsigned short*>(smem + lo) =
                    f2bf(acc[mi][ni][q] + bias);
            }
        }
    }
    __syncthreads();

    // ---- coalesced stores ----
    if (n0 < 256) {
        // Q half: 8 x dwordx4 bf16 per thread
        char* obase = (char*)o_bf0 + (size_t)n0 * 2;
#pragma unroll
        for (int i = 0; i < 8; ++i) {
            int o = i * 4096 + t * 16;
            int row = o >> 8;
            int lo = o ^ ((row & 7) << 4);
            if (m0 + row < M_NODES) {
                short8 v = *reinterpret_cast<const short8*>(smem + lo);
                *reinterpret_cast<short8*>(obase + (size_t)(m0 + row) * 512 + (o & 255)) = v;
            }
        }
    } else {
        // K half: bf16 -> fp8, 8 x 8B stores per thread
        unsigned char* obase = o_fp8 + (n0 - 256);
#pragma unroll
        for (int i = 0; i < 8; ++i) {
            int o = i * 4096 + t * 16;
            int row = o >> 8;
            int lo = o ^ ((row & 7) << 4);
            if (m0 + row < M_NODES) {
                union { short8 v; unsigned u[4]; } c;
                c.v = *reinterpret_cast<const short8*>(smem + lo);
                uint2 pk;
                pk.x = __builtin_amdgcn_cvt_pk_fp8_f32(bflo(c.u[0]), bfhi(c.u[0]), 0, false);
                pk.x = __builtin_amdgcn_cvt_pk_fp8_f32(bflo(c.u[1]), bfhi(c.u[1]), pk.x, true);
                pk.y = __builtin_amdgcn_cvt_pk_fp8_f32(bflo(c.u[2]), bfhi(c.u[2]), 0, false);
                pk.y = __builtin_amdgcn_cvt_pk_fp8_f32(bflo(c.u[3]), bfhi(c.u[3]), pk.y, true);
                *reinterpret_cast<uint2*>(obase + (size_t)(m0 + row) * 256 + ((o & 255) >> 1)) = pk;
            }
        }
    }
}

// ---------------------------------------------------------------------------
// Attention (r16 form, best measured): ONE WAVE per node, no LDS, no
// barriers. kw[16] fp8 rows loaded upfront, single fused pass. Residual
// read from fp32 h (r4-r8 proven; hb eliminated).
// ---------------------------------------------------------------------------
__global__ __launch_bounds__(256) void attn_kernel(
    const float* __restrict__ h,
    const int* __restrict__ nbr_idx,
    const void* __restrict__ nbr_mask_raw,
    const unsigned short* __restrict__ Qb,
    const unsigned char* __restrict__ K8,
    unsigned short* __restrict__ Ctxb)
{
    const int wid  = threadIdx.x >> 6;
    const int lane = threadIdx.x & 63;
    const int n    = blockIdx.x * 4 + wid;

    // ---- mask dtype detect: lane l inspects word l of first 256 bytes ----
    const unsigned int* mw = (const unsigned int*)nbr_mask_raw;
    unsigned long long det = __ballot((mw[lane] & 0xFFFFFF00u) != 0u);
    const bool is_byte = (det != 0ull);

    // ---- per-node mask bits + neighbor idx (lanes 0..15) ----
    unsigned int mbit = 0;
    int idxv = 0;
    if (lane < K_NBR) {
        if (is_byte) mbit = ((const unsigned char*)nbr_mask_raw)[n * K_NBR + lane] ? 1u : 0u;
        else         mbit = ((const int*)nbr_mask_raw)[n * K_NBR + lane] ? 1u : 0u;
        idxv = nbr_idx[n * K_NBR + lane];
    }
    unsigned long long bal = __ballot(mbit != 0u);
    const unsigned int mask16 = (unsigned int)(bal & 0xFFFFull);

    // ---- compacted row list; exhausted slots -> bias-sentinel row ----
    int rows[K_NBR];
    unsigned int mm = mask16;
#pragma unroll
    for (int s = 0; s < K_NBR; ++s) {
        int j = __ffs(mm) - 1;                 // wave-uniform
        int r = __shfl(idxv, (j < 0) ? 0 : j, 64);
        rows[s] = (j >= 0) ? r : M_NODES;      // row M_NODES holds fp8(bk)
        mm &= mm - 1;
    }

    // ---- coalesced per-node loads ----
    const float4 h4 = *reinterpret_cast<const float4*>(h + (size_t)n * DIM + 4 * lane);
    const uint2  qp = *reinterpret_cast<const uint2*>(Qb + (size_t)n * DIM + 4 * lane);

    // ---- gather all 16 kv rows upfront: one dword (4 fp8) per slot ----
    unsigned kw[K_NBR];
#pragma unroll
    for (int s = 0; s < K_NBR; ++s)
        kw[s] = *reinterpret_cast<const unsigned*>(K8 + (size_t)rows[s] * 256 + 4 * lane);

    const float q0 = bflo(qp.x), q1 = bfhi(qp.x), q2 = bflo(qp.y), q3 = bfhi(qp.y);

    // ---- SINGLE fused pass: decode once -> dot -> weight -> accumulate ----
    float c0 = 0.f, c1 = 0.f, c2 = 0.f, c3 = 0.f, wsum = 0.f;
#pragma unroll
    for (int s = 0; s < K_NBR; ++s) {
        f32x2 klo = __builtin_amdgcn_cvt_pk_f32_fp8(kw[s], false);  // bytes 0,1
        f32x2 khi = __builtin_amdgcn_cvt_pk_f32_fp8(kw[s], true);   // bytes 2,3

        float a = q0 * klo.x + q1 * klo.y + q2 * khi.x + q3 * khi.y;
        a += __shfl_xor(a, 1, 8);
        a += __shfl_xor(a, 2, 8);
        a += __shfl_xor(a, 4, 8);              // full 32-dim dot, head = lane>>3

        float sig = fast_rcp(1.0f + fast_exp2(a * NEG_IS_L2E));
        float v = ((mask16 >> s) & 1u) ? sig : 0.0f;
        float e = fast_exp2(v * LOG2E);        // no max-shift: v in [0,1]
        c0 = fmaf(e, klo.x, c0);
        c1 = fmaf(e, klo.y, c1);
        c2 = fmaf(e, khi.x, c2);
        c3 = fmaf(e, khi.y, c3);
        wsum += e;
    }
    const float inv = fast_rcp(wsum);

    const float r0 = h4.x + c0 * inv;
    const float r1 = h4.y + c1 * inv;
    const float r2 = h4.z + c2 * inv;
    const float r3 = h4.w + c3 * inv;

    uint2 o;
    o.x = cvt_pk_bf16(r0, r1);
    o.y = cvt_pk_bf16(r2, r3);
    *reinterpret_cast<uint2*>(Ctxb + (size_t)n * DIM + 4 * lane) = o;
}

// ---------------------------------------------------------------------------
// Output GEMM fused with LayerNorm (r16 epilogue — the r17 transposed store
// measured neutral, reverted). 512 threads = 8 waves (2 row x 4 col),
// tile 128 rows x 256 cols, K in 4 chunks of 64.
// ---------------------------------------------------------------------------
__global__ __launch_bounds__(512) void gemm_out_ln_kernel(
    const unsigned short* __restrict__ A,    // Ctx bf16 [M][256]
    const unsigned short* __restrict__ Bt,   // WoT bf16 [256][256]
    const float* __restrict__ bo,
    const float* __restrict__ gamma, const float* __restrict__ beta,
    float* __restrict__ out)
{
    __shared__ __align__(16) char sA[128 * 128];   // 16 KB (128 rows x 128B)
    __shared__ __align__(16) char sB[256 * 128];   // 32 KB
    __shared__ float part[4][128][2];              // per-wc row partials
    __shared__ float muinv[128][2];
    const int m0 = blockIdx.x * 128;
    const int t = threadIdx.x;
    const int lane = t & 63;
    const int w = t >> 6;            // 0..7
    const int wr = w >> 2, wc = w & 3;

    f32x4 acc[4][4];
#pragma unroll
    for (int a = 0; a < 4; ++a)
#pragma unroll
        for (int b = 0; b < 4; ++b) acc[a][b] = (f32x4){0.f, 0.f, 0.f, 0.f};

    const char* Ab = (const char*)A;
    const char* Bb = (const char*)Bt;

    for (int kt = 0; kt < 512; kt += 128) {   // 4 K-chunks of 64 elems (128B)
#pragma unroll
        for (int i = 0; i < 2; ++i) {         // stage A: 16 KB
            int o = i * 8192 + t * 16;
            int row = o >> 7, col = o & 127;
            int lo = o ^ ((row & 7) << 4);
            int ga = m0 + row; ga = (ga < M_NODES) ? ga : (M_NODES - 1);
            short8 va = *reinterpret_cast<const short8*>(Ab + (size_t)ga * 512 + kt + col);
            *reinterpret_cast<short8*>(sA + lo) = va;
        }
#pragma unroll
        for (int i = 0; i < 4; ++i) {         // stage B: 32 KB
            int o = i * 8192 + t * 16;
            int row = o >> 7, col = o & 127;
            int lo = o ^ ((row & 7) << 4);
            short8 vb = *reinterpret_cast<const short8*>(Bb + (size_t)row * 512 + kt + col);
            *reinterpret_cast<short8*>(sB + lo) = vb;
        }
        __syncthreads();
#pragma unroll
        for (int ks = 0; ks < 2; ++ks) {
            const int kb = ks * 64 + (lane >> 4) * 16;
            short8 af[4], bfr[4];
#pragma unroll
            for (int mi = 0; mi < 4; ++mi) {
                int row = wr * 64 + mi * 16 + (lane & 15);
                af[mi] = *reinterpret_cast<const short8*>(
                    sA + ((row << 7) | (kb ^ ((row & 7) << 4))));
            }
#pragma unroll
            for (int ni = 0; ni < 4; ++ni) {
                int row = wc * 64 + ni * 16 + (lane & 15);
                bfr[ni] = *reinterpret_cast<const short8*>(
                    sB + ((row << 7) | (kb ^ ((row & 7) << 4))));
            }
#pragma unroll
            for (int mi = 0; mi < 4; ++mi)
#pragma unroll
                for (int ni = 0; ni < 4; ++ni)
                    acc[mi][ni] = __builtin_amdgcn_mfma_f32_16x16x32_bf16(
                        af[mi], bfr[ni], acc[mi][ni], 0, 0, 0);
        }
        __syncthreads();
    }

    // ---- LN stats: per-row sum/sumsq ----
    float bias4[4];
#pragma unroll
    for (int ni = 0; ni < 4; ++ni) bias4[ni] = bo[wc * 64 + ni * 16 + (lane & 15)];

#pragma unroll
    for (int mi = 0; mi < 4; ++mi) {
#pragma unroll
        for (int q = 0; q < 4; ++q) {
            float s = 0.f, sq = 0.f;
#pragma unroll
            for (int ni = 0; ni < 4; ++ni) {
                float v = acc[mi][ni][q] + bias4[ni];
                s += v; sq += v * v;
            }
            s  += __shfl_xor(s, 1, 16);  sq += __shfl_xor(sq, 1, 16);
            s  += __shfl_xor(s, 2, 16);  sq += __shfl_xor(sq, 2, 16);
            s  += __shfl_xor(s, 4, 16);  sq += __shfl_xor(sq, 4, 16);
            s  += __shfl_xor(s, 8, 16);  sq += __shfl_xor(sq, 8, 16);
            int lrow = wr * 64 + mi * 16 + (lane >> 4) * 4 + q;
            if ((lane & 15) == 0) { part[wc][lrow][0] = s; part[wc][lrow][1] = sq; }
        }
    }
    __syncthreads();
    if (t < 128) {
        float s  = part[0][t][0] + part[1][t][0] + part[2][t][0] + part[3][t][0];
        float sq = part[0][t][1] + part[1][t][1] + part[2][t][1] + part[3][t][1];
        float mu  = s * (1.f / 256.f);
        float var = sq * (1.f / 256.f) - mu * mu;
        muinv[t][0] = mu;
        muinv[t][1] = rsqrtf(var + EPS);
    }
    __syncthreads();

    // ---- normalize + store ----
    float g4[4], be4[4];
#pragma unroll
    for (int ni = 0; ni < 4; ++ni) {
        int gcol = wc * 64 + ni * 16 + (lane & 15);
        g4[ni] = gamma[gcol];
        be4[ni] = beta[gcol];
    }
#pragma unroll
    for (int mi = 0; mi < 4; ++mi) {
#pragma unroll
        for (int q = 0; q < 4; ++q) {
            int lrow = wr * 64 + mi * 16 + (lane >> 4) * 4 + q;
            int grow = m0 + lrow;
            float mu  = muinv[lrow][0];
            float inv = muinv[lrow][1];
            if (grow < M_NODES) {
#pragma unroll
                for (int ni = 0; ni < 4; ++ni) {
                    int gcol = wc * 64 + ni * 16 + (lane & 15);
                    float v = acc[mi][ni][q] + bias4[ni];
                    out[(size_t)grow * 256 + gcol] = (v - mu) * inv * g4[ni] + be4[ni];
                }
            }
        }
    }
}

// ---------------------------------------------------------------------------
extern "C" void kernel_launch(void* const* d_in, const int* in_sizes, int n_in,
                              void* d_out, int out_size, void* d_ws, size_t ws_size,
                              hipStream_t stream) {
    const float* h       = (const float*)d_in[0];
    const int* nbr_idx   = (const int*)d_in[1];
    const void* nbr_mask = (const void*)d_in[2];
    const float* Wq_w    = (const float*)d_in[3];
    const float* Wq_b    = (const float*)d_in[4];
    const float* Wk_w    = (const float*)d_in[5];
    const float* Wk_b    = (const float*)d_in[6];
    const float* Wo_w    = (const float*)d_in[7];
    const float* Wo_b    = (const float*)d_in[8];
    const float* gamma   = (const float*)d_in[9];
    const float* beta    = (const float*)d_in[10];
    float* out = (float*)d_out;

    // ws layout (bytes): [Qb/Ctxb 25.6M][K8 12.8M + 256 (row 50000 = fp8 bias)]
    //                    [WqkT 256K][WoT 128K]   (hb eliminated)
    char* ws = (char*)d_ws;
    unsigned short* Qb     = (unsigned short*)(ws);
    unsigned char*  K8     = (unsigned char*)(ws + 25600000);
    unsigned char*  Kbias8 = K8 + (size_t)M_NODES * 256;      // row 50000
    unsigned short* WqkT   = (unsigned short*)(ws + 38400256);
    unsigned short* WoT    = (unsigned short*)(ws + 38662400);

    hipLaunchKernelGGL(prep_w_kernel, dim3(769), dim3(256), 0, stream,
                       Wq_w, Wk_w, Wo_w, Wk_b, WqkT, WoT, Kbias8);
    hipLaunchKernelGGL(gemm_qk_kernel, dim3(4, 391), dim3(256), 0, stream,
                       h, WqkT, Wq_b, Wk_b, Qb, K8);
    hipLaunchKernelGGL(attn_kernel, dim3(12500), dim3(256), 0, stream,
                       h, nbr_idx, nbr_mask, Qb, K8, Qb /*Ctx aliases Q*/);
    hipLaunchKernelGGL(gemm_out_ln_kernel, dim3(391), dim3(512), 0, stream,
                       Qb /*Ctx*/, WoT, Wo_b, gamma, beta, out);
}

// Round 19
// 122.279 us; speedup vs baseline: 1.1078x; 1.1078x over previous
//
#include <hip/hip_runtime.h>
#include <hip/hip_bf16.h>
#include <math.h>

#define M_NODES 50000
#define K_NBR   16
#define DIM     256
#define H_HEADS 8
#define EPS     1e-5f
#define INV_SCALE 0.17677669529663687f   // 1/sqrt(32)
#define LOG2E     1.4426950408889634f
#define NEG_IS_L2E (-0.25506150946889375f) // -INV_SCALE*log2(e)

typedef __attribute__((ext_vector_type(8))) short short8;
typedef __attribute__((ext_vector_type(4))) float f32x4;
typedef __attribute__((ext_vector_type(2))) float f32x2;
typedef __attribute__((ext_vector_type(4))) unsigned short ushort4v;

__device__ __forceinline__ unsigned short f2bf(float f) {
    unsigned x = __float_as_uint(f);
    x += 0x7FFFu + ((x >> 16) & 1u);          // round-to-nearest-even
    return (unsigned short)(x >> 16);
}
__device__ __forceinline__ unsigned cvt_pk_bf16(float lo, float hi) {
    unsigned r;
    asm volatile("v_cvt_pk_bf16_f32 %0, %1, %2" : "=v"(r) : "v"(lo), "v"(hi));
    return r;
}
__device__ __forceinline__ float bflo(unsigned int u) {   // low bf16 of dword
    return __uint_as_float(u << 16);
}
__device__ __forceinline__ float bfhi(unsigned int u) {   // high bf16 of dword
    return __uint_as_float(u & 0xFFFF0000u);
}
__device__ __forceinline__ float fast_exp2(float x) {     // v_exp_f32: 2^x
    float r; asm("v_exp_f32 %0, %1" : "=v"(r) : "v"(x)); return r;
}
__device__ __forceinline__ float fast_rcp(float x) {      // v_rcp_f32 (~1ulp)
    float r; asm("v_rcp_f32 %0, %1" : "=v"(r) : "v"(x)); return r;
}

// ---------------------------------------------------------------------------
// Kernel 0: h -> bf16 (13k-block TLP hides the conversion — fusing this into
// gemm_qk regressed TWICE, r9/r18: VGPR 96 -> 2 blocks/CU); transposed bf16
// weights; fp8 bias-sentinel row K8[M_NODES] = fp8(bk).
// ---------------------------------------------------------------------------
__global__ __launch_bounds__(256) void prep_kernel(
    const float* __restrict__ h, const float* __restrict__ Wq,
    const float* __restrict__ Wk, const float* __restrict__ Wo,
    const float* __restrict__ bk,
    unsigned short* __restrict__ hb, unsigned short* __restrict__ WqkT,
    unsigned short* __restrict__ WoT, unsigned char* __restrict__ Kbias8)
{
    const int NH4 = M_NODES * DIM / 4;  // 3,200,000 float4 groups
    int i = blockIdx.x * 256 + threadIdx.x;
    if (i < NH4) {
        float4 v = reinterpret_cast<const float4*>(h)[i];
        ushort4v o;
        o.x = f2bf(v.x); o.y = f2bf(v.y); o.z = f2bf(v.z); o.w = f2bf(v.w);
        reinterpret_cast<ushort4v*>(hb)[i] = o;
    } else if (i < NH4 + 512 * 256) {
        int j = i - NH4; int n = j >> 8, k = j & 255;
        float v = (n < 256) ? Wq[k * 256 + n] : Wk[k * 256 + (n - 256)];
        WqkT[j] = f2bf(v);
    } else if (i < NH4 + 512 * 256 + 256 * 256) {
        int j = i - NH4 - 512 * 256; int n = j >> 8, k = j & 255;
        WoT[j] = f2bf(Wo[k * 256 + n]);
    } else if (i < NH4 + 512 * 256 + 256 * 256 + 256) {
        int j = i - NH4 - 512 * 256 - 256 * 256;   // 0..255
        unsigned r8v = __builtin_amdgcn_cvt_pk_fp8_f32(bk[j], bk[j], 0, false);
        Kbias8[j] = (unsigned char)(r8v & 0xFFu);
    }
}

// ---------------------------------------------------------------------------
// GEMM QK: [Q|K] = hb @ WqkT^T + [bq|bk]. Q half -> bf16, K half -> fp8 e4m3
// (halves the attn gather bytes). 128x128 tile, 4 waves, 16x16x32 bf16 MFMA,
// K staged in 4 chunks of 64 (sA/sB 16KB). LDS-transpose epilogue: C-tile
// (bf16) staged into the dead 32KB, re-read row-major; Q stores dwordx4,
// K stores convert bf16->fp8 and store 8B/thread (coalesced).
// ---------------------------------------------------------------------------
__global__ __launch_bounds__(256) void gemm_qk_kernel(
    const unsigned short* __restrict__ A,
    const unsigned short* __restrict__ Bt,
    const float* __restrict__ bias0, const float* __restrict__ bias1,
    unsigned short* __restrict__ o_bf0, unsigned char* __restrict__ o_fp8)
{
    __shared__ __align__(16) char smem[32768];    // sA 16KB | sB 16KB; epilogue: C-tile
    char* sA = smem;
    char* sB = smem + 16384;
    const int m0 = blockIdx.y * 128;
    const int n0 = blockIdx.x * 128;
    const int t = threadIdx.x;
    const int lane = t & 63;
    const int w = t >> 6;
    const int wr = w >> 1, wc = w & 1;

    f32x4 acc[4][4];
#pragma unroll
    for (int a = 0; a < 4; ++a)
#pragma unroll
        for (int b = 0; b < 4; ++b) acc[a][b] = (f32x4){0.f, 0.f, 0.f, 0.f};

    const char* Ab = (const char*)A;
    const char* Bb = (const char*)Bt;

    for (int kt = 0; kt < 512; kt += 128) {  // 4 chunks of 64 elems (128B)
#pragma unroll
        for (int i = 0; i < 4; ++i) {
            int o = i * 4096 + t * 16;
            int row = o >> 7;
            int col = o & 127;
            int lo = o ^ ((row & 7) << 4);
            int ga = m0 + row; ga = (ga < M_NODES) ? ga : (M_NODES - 1);
            short8 va = *reinterpret_cast<const short8*>(Ab + (size_t)ga * 512 + kt + col);
            *reinterpret_cast<short8*>(sA + lo) = va;
            int gb = n0 + row;
            short8 vb = *reinterpret_cast<const short8*>(Bb + (size_t)gb * 512 + kt + col);
            *reinterpret_cast<short8*>(sB + lo) = vb;
        }
        __syncthreads();
#pragma unroll
        for (int ks = 0; ks < 2; ++ks) {
            const int kb = ks * 64 + (lane >> 4) * 16;
            short8 af[4], bfr[4];
#pragma unroll
            for (int mi = 0; mi < 4; ++mi) {
                int row = wr * 64 + mi * 16 + (lane & 15);
                af[mi] = *reinterpret_cast<const short8*>(
                    sA + ((row << 7) | (kb ^ ((row & 7) << 4))));
            }
#pragma unroll
            for (int ni = 0; ni < 4; ++ni) {
                int row = wc * 64 + ni * 16 + (lane & 15);
                bfr[ni] = *reinterpret_cast<const short8*>(
                    sB + ((row << 7) | (kb ^ ((row & 7) << 4))));
            }
#pragma unroll
            for (int mi = 0; mi < 4; ++mi)
#pragma unroll
                for (int ni = 0; ni < 4; ++ni)
                    acc[mi][ni] = __builtin_amdgcn_mfma_f32_16x16x32_bf16(
                        af[mi], bfr[ni], acc[mi][ni], 0, 0, 0);
        }
        __syncthreads();
    }

    // ---- epilogue: bias + f2bf into LDS C-tile (row*256B + col*2, XOR-swz) ----
#pragma unroll
    for (int ni = 0; ni < 4; ++ni) {
        int lcol = wc * 64 + ni * 16 + (lane & 15);
        int gcol = n0 + lcol;
        float bias = (gcol < 256) ? bias0[gcol] : bias1[gcol - 256];
#pragma unroll
        for (int mi = 0; mi < 4; ++mi) {
#pragma unroll
            for (int q = 0; q < 4; ++q) {
                int lrow = wr * 64 + mi * 16 + (lane >> 4) * 4 + q;
                int o = (lrow << 8) + lcol * 2;
                int lo = o ^ ((lrow & 7) << 4);
                *reinterpret_cast<unsigned short*>(smem + lo) =
                    f2bf(acc[mi][ni][q] + bias);
            }
        }
    }
    __syncthreads();

    // ---- coalesced stores ----
    if (n0 < 256) {
        // Q half: 8 x dwordx4 bf16 per thread
        char* obase = (char*)o_bf0 + (size_t)n0 * 2;
#pragma unroll
        for (int i = 0; i < 8; ++i) {
            int o = i * 4096 + t * 16;
            int row = o >> 8;
            int lo = o ^ ((row & 7) << 4);
            if (m0 + row < M_NODES) {
                short8 v = *reinterpret_cast<const short8*>(smem + lo);
                *reinterpret_cast<short8*>(obase + (size_t)(m0 + row) * 512 + (o & 255)) = v;
            }
        }
    } else {
        // K half: bf16 -> fp8, 8 x 8B stores per thread
        unsigned char* obase = o_fp8 + (n0 - 256);
#pragma unroll
        for (int i = 0; i < 8; ++i) {
            int o = i * 4096 + t * 16;
            int row = o >> 8;
            int lo = o ^ ((row & 7) << 4);
            if (m0 + row < M_NODES) {
                union { short8 v; unsigned u[4]; } c;
                c.v = *reinterpret_cast<const short8*>(smem + lo);
                uint2 pk;
                pk.x = __builtin_amdgcn_cvt_pk_fp8_f32(bflo(c.u[0]), bfhi(c.u[0]), 0, false);
                pk.x = __builtin_amdgcn_cvt_pk_fp8_f32(bflo(c.u[1]), bfhi(c.u[1]), pk.x, true);
                pk.y = __builtin_amdgcn_cvt_pk_fp8_f32(bflo(c.u[2]), bfhi(c.u[2]), 0, false);
                pk.y = __builtin_amdgcn_cvt_pk_fp8_f32(bflo(c.u[3]), bfhi(c.u[3]), pk.y, true);
                *reinterpret_cast<uint2*>(obase + (size_t)(m0 + row) * 256 + ((o & 255) >> 1)) = pk;
            }
        }
    }
}

// ---------------------------------------------------------------------------
// Attention (r16 form, best measured): ONE WAVE per node, no LDS, no
// barriers. kw[16] fp8 rows loaded upfront, single fused pass:
// pk-decode once -> dot -> shuffle-reduce -> sigmoid-weight -> accumulate.
// No max-shift (sigmoid in [0,1]). Padded slots hit fp8 bias-sentinel row.
// ---------------------------------------------------------------------------
__global__ __launch_bounds__(256) void attn_kernel(
    const unsigned short* __restrict__ hb,
    const int* __restrict__ nbr_idx,
    const void* __restrict__ nbr_mask_raw,
    const unsigned short* __restrict__ Qb,
    const unsigned char* __restrict__ K8,
    unsigned short* __restrict__ Ctxb)
{
    const int wid  = threadIdx.x >> 6;
    const int lane = threadIdx.x & 63;
    const int n    = blockIdx.x * 4 + wid;

    // ---- mask dtype detect: lane l inspects word l of first 256 bytes ----
    const unsigned int* mw = (const unsigned int*)nbr_mask_raw;
    unsigned long long det = __ballot((mw[lane] & 0xFFFFFF00u) != 0u);
    const bool is_byte = (det != 0ull);

    // ---- per-node mask bits + neighbor idx (lanes 0..15) ----
    unsigned int mbit = 0;
    int idxv = 0;
    if (lane < K_NBR) {
        if (is_byte) mbit = ((const unsigned char*)nbr_mask_raw)[n * K_NBR + lane] ? 1u : 0u;
        else         mbit = ((const int*)nbr_mask_raw)[n * K_NBR + lane] ? 1u : 0u;
        idxv = nbr_idx[n * K_NBR + lane];
    }
    unsigned long long bal = __ballot(mbit != 0u);
    const unsigned int mask16 = (unsigned int)(bal & 0xFFFFull);

    // ---- compacted row list; exhausted slots -> bias-sentinel row ----
    int rows[K_NBR];
    unsigned int mm = mask16;
#pragma unroll
    for (int s = 0; s < K_NBR; ++s) {
        int j = __ffs(mm) - 1;                 // wave-uniform
        int r = __shfl(idxv, (j < 0) ? 0 : j, 64);
        rows[s] = (j >= 0) ? r : M_NODES;      // row M_NODES holds fp8(bk)
        mm &= mm - 1;
    }

    // ---- coalesced per-node loads ----
    const uint2 hp = *reinterpret_cast<const uint2*>(hb + (size_t)n * DIM + 4 * lane);
    const uint2 qp = *reinterpret_cast<const uint2*>(Qb + (size_t)n * DIM + 4 * lane);

    // ---- gather all 16 kv rows upfront: one dword (4 fp8) per slot ----
    unsigned kw[K_NBR];
#pragma unroll
    for (int s = 0; s < K_NBR; ++s)
        kw[s] = *reinterpret_cast<const unsigned*>(K8 + (size_t)rows[s] * 256 + 4 * lane);

    const float q0 = bflo(qp.x), q1 = bfhi(qp.x), q2 = bflo(qp.y), q3 = bfhi(qp.y);

    // ---- SINGLE fused pass: decode once -> dot -> weight -> accumulate ----
    float c0 = 0.f, c1 = 0.f, c2 = 0.f, c3 = 0.f, wsum = 0.f;
#pragma unroll
    for (int s = 0; s < K_NBR; ++s) {
        f32x2 klo = __builtin_amdgcn_cvt_pk_f32_fp8(kw[s], false);  // bytes 0,1
        f32x2 khi = __builtin_amdgcn_cvt_pk_f32_fp8(kw[s], true);   // bytes 2,3

        float a = q0 * klo.x + q1 * klo.y + q2 * khi.x + q3 * khi.y;
        a += __shfl_xor(a, 1, 8);
        a += __shfl_xor(a, 2, 8);
        a += __shfl_xor(a, 4, 8);              // full 32-dim dot, head = lane>>3

        float sig = fast_rcp(1.0f + fast_exp2(a * NEG_IS_L2E));
        float v = ((mask16 >> s) & 1u) ? sig : 0.0f;
        float e = fast_exp2(v * LOG2E);        // no max-shift: v in [0,1]
        c0 = fmaf(e, klo.x, c0);
        c1 = fmaf(e, klo.y, c1);
        c2 = fmaf(e, khi.x, c2);
        c3 = fmaf(e, khi.y, c3);
        wsum += e;
    }
    const float inv = fast_rcp(wsum);

    const float r0 = bflo(hp.x) + c0 * inv;
    const float r1 = bfhi(hp.x) + c1 * inv;
    const float r2 = bflo(hp.y) + c2 * inv;
    const float r3 = bfhi(hp.y) + c3 * inv;

    uint2 o;
    o.x = cvt_pk_bf16(r0, r1);
    o.y = cvt_pk_bf16(r2, r3);
    *reinterpret_cast<uint2*>(Ctxb + (size_t)n * DIM + 4 * lane) = o;
}

// ---------------------------------------------------------------------------
// Output GEMM fused with LayerNorm. 512 threads = 8 waves (2 row x 4 col),
// tile 128 rows x 256 cols, K in 4 chunks of 64. Row mean/var via 16-lane
// swizzle reduce -> LDS cross-wave combine -> normalize from accumulators.
// ---------------------------------------------------------------------------
__global__ __launch_bounds__(512) void gemm_out_ln_kernel(
    const unsigned short* __restrict__ A,    // Ctx bf16 [M][256]
    const unsigned short* __restrict__ Bt,   // WoT bf16 [256][256]
    const float* __restrict__ bo,
    const float* __restrict__ gamma, const float* __restrict__ beta,
    float* __restrict__ out)
{
    __shared__ __align__(16) char sA[128 * 128];   // 16 KB (128 rows x 128B)
    __shared__ __align__(16) char sB[256 * 128];   // 32 KB
    __shared__ float part[4][128][2];              // per-wc row partials
    __shared__ float muinv[128][2];
    const int m0 = blockIdx.x * 128;
    const int t = threadIdx.x;
    const int lane = t & 63;
    const int w = t >> 6;            // 0..7
    const int wr = w >> 2, wc = w & 3;

    f32x4 acc[4][4];
#pragma unroll
    for (int a = 0; a < 4; ++a)
#pragma unroll
        for (int b = 0; b < 4; ++b) acc[a][b] = (f32x4){0.f, 0.f, 0.f, 0.f};

    const char* Ab = (const char*)A;
    const char* Bb = (const char*)Bt;

    for (int kt = 0; kt < 512; kt += 128) {   // 4 K-chunks of 64 elems (128B)
#pragma unroll
        for (int i = 0; i < 2; ++i) {         // stage A: 16 KB
            int o = i * 8192 + t * 16;
            int row = o >> 7, col = o & 127;
            int lo = o ^ ((row & 7) << 4);
            int ga = m0 + row; ga = (ga < M_NODES) ? ga : (M_NODES - 1);
            short8 va = *reinterpret_cast<const short8*>(Ab + (size_t)ga * 512 + kt + col);
            *reinterpret_cast<short8*>(sA + lo) = va;
        }
#pragma unroll
        for (int i = 0; i < 4; ++i) {         // stage B: 32 KB
            int o = i * 8192 + t * 16;
            int row = o >> 7, col = o & 127;
            int lo = o ^ ((row & 7) << 4);
            short8 vb = *reinterpret_cast<const short8*>(Bb + (size_t)row * 512 + kt + col);
            *reinterpret_cast<short8*>(sB + lo) = vb;
        }
        __syncthreads();
#pragma unroll
        for (int ks = 0; ks < 2; ++ks) {
            const int kb = ks * 64 + (lane >> 4) * 16;
            short8 af[4], bfr[4];
#pragma unroll
            for (int mi = 0; mi < 4; ++mi) {
                int row = wr * 64 + mi * 16 + (lane & 15);
                af[mi] = *reinterpret_cast<const short8*>(
                    sA + ((row << 7) | (kb ^ ((row & 7) << 4))));
            }
#pragma unroll
            for (int ni = 0; ni < 4; ++ni) {
                int row = wc * 64 + ni * 16 + (lane & 15);
                bfr[ni] = *reinterpret_cast<const short8*>(
                    sB + ((row << 7) | (kb ^ ((row & 7) << 4))));
            }
#pragma unroll
            for (int mi = 0; mi < 4; ++mi)
#pragma unroll
                for (int ni = 0; ni < 4; ++ni)
                    acc[mi][ni] = __builtin_amdgcn_mfma_f32_16x16x32_bf16(
                        af[mi], bfr[ni], acc[mi][ni], 0, 0, 0);
        }
        __syncthreads();
    }

    // ---- LN stats: per-row sum/sumsq ----
    float bias4[4];
#pragma unroll
    for (int ni = 0; ni < 4; ++ni) bias4[ni] = bo[wc * 64 + ni * 16 + (lane & 15)];

#pragma unroll
    for (int mi = 0; mi < 4; ++mi) {
#pragma unroll
        for (int q = 0; q < 4; ++q) {
            float s = 0.f, sq = 0.f;
#pragma unroll
            for (int ni = 0; ni < 4; ++ni) {
                float v = acc[mi][ni][q] + bias4[ni];
                s += v; sq += v * v;
            }
            s  += __shfl_xor(s, 1, 16);  sq += __shfl_xor(sq, 1, 16);
            s  += __shfl_xor(s, 2, 16);  sq += __shfl_xor(sq, 2, 16);
            s  += __shfl_xor(s, 4, 16);  sq += __shfl_xor(sq, 4, 16);
            s  += __shfl_xor(s, 8, 16);  sq += __shfl_xor(sq, 8, 16);
            int lrow = wr * 64 + mi * 16 + (lane >> 4) * 4 + q;
            if ((lane & 15) == 0) { part[wc][lrow][0] = s; part[wc][lrow][1] = sq; }
        }
    }
    __syncthreads();
    if (t < 128) {
        float s  = part[0][t][0] + part[1][t][0] + part[2][t][0] + part[3][t][0];
        float sq = part[0][t][1] + part[1][t][1] + part[2][t][1] + part[3][t][1];
        float mu  = s * (1.f / 256.f);
        float var = sq * (1.f / 256.f) - mu * mu;
        muinv[t][0] = mu;
        muinv[t][1] = rsqrtf(var + EPS);
    }
    __syncthreads();

    // ---- normalize + store ----
    float g4[4], be4[4];
#pragma unroll
    for (int ni = 0; ni < 4; ++ni) {
        int gcol = wc * 64 + ni * 16 + (lane & 15);
        g4[ni] = gamma[gcol];
        be4[ni] = beta[gcol];
    }
#pragma unroll
    for (int mi = 0; mi < 4; ++mi) {
#pragma unroll
        for (int q = 0; q < 4; ++q) {
            int lrow = wr * 64 + mi * 16 + (lane >> 4) * 4 + q;
            int grow = m0 + lrow;
            float mu  = muinv[lrow][0];
            float inv = muinv[lrow][1];
            if (grow < M_NODES) {
#pragma unroll
                for (int ni = 0; ni < 4; ++ni) {
                    int gcol = wc * 64 + ni * 16 + (lane & 15);
                    float v = acc[mi][ni][q] + bias4[ni];
                    out[(size_t)grow * 256 + gcol] = (v - mu) * inv * g4[ni] + be4[ni];
                }
            }
        }
    }
}

// ---------------------------------------------------------------------------
extern "C" void kernel_launch(void* const* d_in, const int* in_sizes, int n_in,
                              void* d_out, int out_size, void* d_ws, size_t ws_size,
                              hipStream_t stream) {
    const float* h       = (const float*)d_in[0];
    const int* nbr_idx   = (const int*)d_in[1];
    const void* nbr_mask = (const void*)d_in[2];
    const float* Wq_w    = (const float*)d_in[3];
    const float* Wq_b    = (const float*)d_in[4];
    const float* Wk_w    = (const float*)d_in[5];
    const float* Wk_b    = (const float*)d_in[6];
    const float* Wo_w    = (const float*)d_in[7];
    const float* Wo_b    = (const float*)d_in[8];
    const float* gamma   = (const float*)d_in[9];
    const float* beta    = (const float*)d_in[10];
    float* out = (float*)d_out;

    // ws layout (bytes): [Qb/Ctxb 25.6M][K8 12.8M + 256 (row 50000 = fp8 bias)]
    //                    [hb 25.6M][WqkT 256K][WoT 128K]
    char* ws = (char*)d_ws;
    unsigned short* Qb    = (unsigned short*)(ws);
    unsigned char*  K8    = (unsigned char*)(ws + 25600000);
    unsigned char*  Kbias8 = K8 + (size_t)M_NODES * 256;      // row 50000
    unsigned short* hb    = (unsigned short*)(ws + 38400256);
    unsigned short* WqkT  = (unsigned short*)(ws + 64000256);
    unsigned short* WoT   = (unsigned short*)(ws + 64262400);

    hipLaunchKernelGGL(prep_kernel, dim3(13269), dim3(256), 0, stream,
                       h, Wq_w, Wk_w, Wo_w, Wk_b, hb, WqkT, WoT, Kbias8);
    hipLaunchKernelGGL(gemm_qk_kernel, dim3(4, 391), dim3(256), 0, stream,
                       hb, WqkT, Wq_b, Wk_b, Qb, K8);
    hipLaunchKernelGGL(attn_kernel, dim3(12500), dim3(256), 0, stream,
                       hb, nbr_idx, nbr_mask, Qb, K8, Qb /*Ctx aliases Q*/);
    hipLaunchKernelGGL(gemm_out_ln_kernel, dim3(391), dim3(512), 0, stream,
                       Qb /*Ctx*/, WoT, Wo_b, gamma, beta, out);
}